// Round 13
// baseline (239.187 us; speedup 1.0000x reference)
//
#include <hip/hip_runtime.h>
#include <math.h>

#define N_NODES 100000
#define F_IN    128
#define HID     64
#define N_CLS   40
#define MT      (N_NODES / 16)                  // 6250 M-tiles of 16 nodes

#define BSHIFT  9
#define BSZ     512                              // dsts per coarse bucket
#define NB      ((N_NODES + BSZ - 1) / BSZ)      // 196 buckets
#define EPB     4096                             // edges per block in sort passes

typedef __attribute__((ext_vector_type(8))) short bf8_t;   // 8 bf16 (4 VGPR)
typedef __attribute__((ext_vector_type(4))) float f4_t;    // MFMA C/D frag
typedef __attribute__((ext_vector_type(2))) float f2v_t;

typedef unsigned short ushort_t;
typedef unsigned int uint_t;
typedef unsigned char uchar_t;

__device__ __forceinline__ ushort_t f2b(float f) {   // f32 -> bf16 RNE
    union { float f; uint_t u; } c; c.f = f;
    uint_t u = c.u + 0x7FFFu + ((c.u >> 16) & 1u);
    return (ushort_t)(u >> 16);
}
__device__ __forceinline__ float b2f(ushort_t h) {
    union { uint_t u; float f; } c; c.u = ((uint_t)h) << 16;
    return c.f;
}

// ---- fp8 e4m3 (OCP) helpers: HW cvt if available, manual fallback ---------
#if defined(__has_builtin)
#if __has_builtin(__builtin_amdgcn_cvt_pk_f32_fp8) && __has_builtin(__builtin_amdgcn_cvt_pk_fp8_f32)
#define HAVE_FP8_HW 1
#endif
#endif

__device__ __forceinline__ uchar_t fp8_enc(float v) {
#ifdef HAVE_FP8_HW
    return (uchar_t)(__builtin_amdgcn_cvt_pk_fp8_f32(v, v, 0, false) & 0xff);
#else
    union { float f; uint_t u; } c; c.f = v;
    uint_t s = c.u >> 31;
    float av = fabsf(v);
    if (av > 448.f) av = 448.f;
    int e;
    float m = frexpf(av, &e);          // av = m * 2^e, m in [0.5,1)
    int ee = e + 6;                    // biased for e4m3 (bias 7, m in [1,2))
    uchar_t r;
    if (av == 0.f) r = 0;
    else if (ee <= 0) {                // denormal
        int q = (int)(av * 512.f + 0.5f);   // units of 2^-9
        if (q > 7) q = 7;
        r = (uchar_t)q;
    } else {
        int q = (int)(m * 16.f + 0.5f);     // m*16 in [8,16]
        if (q == 16) { q = 8; ee += 1; }
        if (ee > 15) { ee = 15; q = 15; }   // clamp toward max finite
        r = (uchar_t)((ee << 3) | (q & 7));
    }
    return r | (uchar_t)(s << 7);
#endif
}

__device__ __forceinline__ f2v_t fp8x2_dec_lo(uint_t w) {
#ifdef HAVE_FP8_HW
    return __builtin_amdgcn_cvt_pk_f32_fp8(w, false);
#else
    f2v_t r;
    for (int k = 0; k < 2; ++k) {
        uchar_t b = (w >> (8 * k)) & 0xff;
        uint_t s = (b >> 7) & 1, e = (b >> 3) & 15, m = b & 7;
        float f;
        if (e) { union { uint_t u; float ff; } c;
                 c.u = (s << 31) | ((e + 120) << 23) | (m << 20); f = c.ff; }
        else   { f = (float)m * 0.001953125f; if (s) f = -f; }
        r[k] = f;
    }
    return r;
#endif
}
__device__ __forceinline__ f2v_t fp8x2_dec_hi(uint_t w) {
#ifdef HAVE_FP8_HW
    return __builtin_amdgcn_cvt_pk_f32_fp8(w, true);
#else
    return fp8x2_dec_lo(w >> 16);
#endif
}

// ---------------------------------------------------------------------------
// hist_cvt: grid-partitioned fusion. Blocks [0,nblk): per-block LDS histogram
// over 196 coarse buckets. Blocks [nblk, ...): weight conversion to bf16.
// ---------------------------------------------------------------------------
__global__ void hist_cvt_kernel(const int* __restrict__ ei, int E, int nblk,
                                int* __restrict__ blockHist,
                                const float* __restrict__ W1l,
                                const float* __restrict__ W1r,
                                const float* __restrict__ W2l,
                                const float* __restrict__ W2r,
                                ushort_t* __restrict__ W1t,
                                ushort_t* __restrict__ W2t) {
    __shared__ int cnt[NB];
    int t = threadIdx.x;
    if ((int)blockIdx.x < nblk) {
        int blk = blockIdx.x;
        for (int i = t; i < NB; i += 256) cnt[i] = 0;
        __syncthreads();
        int e0 = blk * EPB;
#pragma unroll
        for (int i = 0; i < EPB / 256; ++i) {
            int e = e0 + i * 256 + t;
            if (e < E) atomicAdd(&cnt[ei[E + e] >> BSHIFT], 1);
        }
        __syncthreads();
        for (int i = t; i < NB; i += 256) blockHist[blk * NB + i] = cnt[i];
    } else {
        int u = (blockIdx.x - nblk) * 256 + t;
        if (u < 128 * F_IN) {
            int n = u / F_IN, k = u - n * F_IN;
            float v = (n < HID) ? W1l[k * HID + n] : W1r[k * HID + (n - HID)];
            W1t[u] = f2b(v);
        } else if (u < 128 * F_IN + 80 * HID) {
            int w = u - 128 * F_IN;
            int n = w / HID, k = w - n * HID;
            float v = (n < N_CLS) ? W2l[k * N_CLS + n] : W2r[k * N_CLS + (n - N_CLS)];
            W2t[w] = f2b(v);
        }
    }
}

// ---------------------------------------------------------------------------
// scan_gemm1: grid-partitioned fusion. Blocks [0,NB): per-bin exclusive scan
// down the sort blocks (col_scan). Blocks [NB, ...): gemm1 (independent of
// the sort chain) — its ~25 µs hides the scan entirely.
// ---------------------------------------------------------------------------
__global__ void scan_gemm1_kernel(const int* __restrict__ blockHist, int nblk,
                                  int* __restrict__ blockBase,
                                  int* __restrict__ btot,
                                  const float* __restrict__ x,
                                  const ushort_t* __restrict__ W1t,
                                  uchar_t* __restrict__ y1f8,
                                  ushort_t* __restrict__ z1b) {
    __shared__ int ss[256];
    __shared__ int carry;
    __shared__ uchar_t sy[128][80];    // 10240 B, rows padded 64->80
    __shared__ ushort_t sz[128][72];   // 18432 B, rows padded 64->72
    int t = threadIdx.x;
    if (blockIdx.x < NB) {
        int bin = blockIdx.x;
        if (t == 0) carry = 0;
        __syncthreads();
        for (int c0 = 0; c0 < nblk; c0 += 256) {
            int b = c0 + t;
            int v = (b < nblk) ? blockHist[b * NB + bin] : 0;
            ss[t] = v;
            __syncthreads();
            for (int off = 1; off < 256; off <<= 1) {
                int u = (t >= off) ? ss[t - off] : 0;
                __syncthreads();
                ss[t] += u;
                __syncthreads();
            }
            if (b < nblk) blockBase[b * NB + bin] = carry + ss[t] - v;
            __syncthreads();
            if (t == 255) carry += ss[255];
            __syncthreads();
        }
        if (t == 0) btot[bin] = carry;
        return;
    }
    // ---- gemm1 body (block id rebased) ----
    int gblk = blockIdx.x - NB;
    int tid = t;
    int wave = tid >> 6, lane = tid & 63;
    int tile0 = gblk * 8 + wave * 2;           // 2 consecutive tiles per wave
    int m0b = gblk * 128;
    int r = lane & 15, q = lane >> 4;
    bool v0 = (tile0 < MT), v1 = (tile0 + 1 < MT);

    bf8_t a0[4], a1[4];
#pragma unroll
    for (int kt = 0; kt < 4; ++kt) { a0[kt] = (bf8_t)(short)0; a1[kt] = (bf8_t)(short)0; }
    if (v0) {
        const float* xr = x + (size_t)(tile0 * 16 + r) * F_IN + q * 8;
#pragma unroll
        for (int kt = 0; kt < 4; ++kt) {
            float4 u = *(const float4*)(xr + kt * 32);
            float4 v = *(const float4*)(xr + kt * 32 + 4);
            bf8_t tt;
            tt[0] = (short)f2b(u.x); tt[1] = (short)f2b(u.y);
            tt[2] = (short)f2b(u.z); tt[3] = (short)f2b(u.w);
            tt[4] = (short)f2b(v.x); tt[5] = (short)f2b(v.y);
            tt[6] = (short)f2b(v.z); tt[7] = (short)f2b(v.w);
            a0[kt] = tt;
        }
    }
    if (v1) {
        const float* xr = x + (size_t)((tile0 + 1) * 16 + r) * F_IN + q * 8;
#pragma unroll
        for (int kt = 0; kt < 4; ++kt) {
            float4 u = *(const float4*)(xr + kt * 32);
            float4 v = *(const float4*)(xr + kt * 32 + 4);
            bf8_t tt;
            tt[0] = (short)f2b(u.x); tt[1] = (short)f2b(u.y);
            tt[2] = (short)f2b(u.z); tt[3] = (short)f2b(u.w);
            tt[4] = (short)f2b(v.x); tt[5] = (short)f2b(v.y);
            tt[6] = (short)f2b(v.z); tt[7] = (short)f2b(v.w);
            a1[kt] = tt;
        }
    }
    int lr0 = wave * 32 + q * 4;       // row base within block for tile 0
#pragma unroll
    for (int tn = 0; tn < 8; ++tn) {
        const ushort_t* wr = W1t + (size_t)(tn * 16 + r) * F_IN + q * 8;
        bf8_t b[4];
#pragma unroll
        for (int kt = 0; kt < 4; ++kt)
            b[kt] = *(const bf8_t*)(wr + kt * 32);
        f4_t acc0 = {0.f, 0.f, 0.f, 0.f};
        f4_t acc1 = {0.f, 0.f, 0.f, 0.f};
#pragma unroll
        for (int kt = 0; kt < 4; ++kt) {
            acc0 = __builtin_amdgcn_mfma_f32_16x16x32_bf16(a0[kt], b[kt], acc0, 0, 0, 0);
            acc1 = __builtin_amdgcn_mfma_f32_16x16x32_bf16(a1[kt], b[kt], acc1, 0, 0, 0);
        }
        int col = tn * 16 + r;
        if (col < 64) {
            if (v0) {
#pragma unroll
                for (int rr = 0; rr < 4; ++rr) sy[lr0 + rr][col] = fp8_enc(acc0[rr]);
            }
            if (v1) {
#pragma unroll
                for (int rr = 0; rr < 4; ++rr) sy[lr0 + 16 + rr][col] = fp8_enc(acc1[rr]);
            }
        } else {
            if (v0) {
#pragma unroll
                for (int rr = 0; rr < 4; ++rr) sz[lr0 + rr][col - 64] = f2b(acc0[rr]);
            }
            if (v1) {
#pragma unroll
                for (int rr = 0; rr < 4; ++rr) sz[lr0 + 16 + rr][col - 64] = f2b(acc1[rr]);
            }
        }
    }
    __syncthreads();
    int vrows = N_NODES - m0b; if (vrows > 128) vrows = 128;
    for (int idx = tid; idx < vrows * 4; idx += 256) {
        int row = idx >> 2, c = (idx & 3) << 4;
        *(uint4*)(y1f8 + (size_t)(m0b + row) * 64 + c) = *(const uint4*)&sy[row][c];
    }
    for (int idx = tid; idx < vrows * 8; idx += 256) {
        int row = idx >> 3, c = (idx & 7) << 3;      // ushort offset, 8 = 16 B
        *(uint4*)(z1b + (size_t)(m0b + row) * HID + c) = *(const uint4*)&sz[row][c];
    }
}

// ---------------------------------------------------------------------------
// Sort pass 3: scatter packed (src<<9 | dst&511) into coarse-bucket order.
// Bucket base offsets computed locally from btot (196-elem LDS scan).
// ---------------------------------------------------------------------------
__global__ void scatter_pairs_kernel(const int* __restrict__ ei, int E,
                                     const int* __restrict__ blockBase,
                                     const int* __restrict__ btot,
                                     uint_t* __restrict__ pairs) {
    __shared__ int cur[NB];
    __shared__ int base[NB];
    __shared__ int ss[256];
    int t = threadIdx.x, blk = blockIdx.x;
    int v = (t < NB) ? btot[t] : 0;
    ss[t] = v;
    __syncthreads();
    for (int off = 1; off < 256; off <<= 1) {
        int u = (t >= off) ? ss[t - off] : 0;
        __syncthreads();
        ss[t] += u;
        __syncthreads();
    }
    if (t < NB) {
        cur[t] = 0;
        base[t] = (ss[t] - v) + blockBase[blk * NB + t];
    }
    __syncthreads();
    int e0 = blk * EPB;
#pragma unroll
    for (int i = 0; i < EPB / 256; ++i) {
        int e = e0 + i * 256 + t;
        if (e < E) {
            int src = ei[e];
            int dst = ei[E + e];
            int bin = dst >> BSHIFT;
            int r = atomicAdd(&cur[bin], 1);   // LDS atomic
            pairs[base[bin] + r] = ((uint_t)src << BSHIFT) | (uint_t)(dst & (BSZ - 1));
        }
    }
}

// ---------------------------------------------------------------------------
// Sort pass 4: per-bucket fine sort + rowptr + degree-balanced permutation.
// perm[bin*512 + rank] lists the bucket's nodes in ascending-degree order:
// agg1's waves take 16 consecutive perm entries -> ~equal degrees -> no
// straggling inside the serial edge loop.
// ---------------------------------------------------------------------------
__global__ void bucket_sort_kernel(const uint_t* __restrict__ pairs,
                                   const int* __restrict__ btot,
                                   int* __restrict__ rowptr,
                                   int* __restrict__ csr,
                                   int* __restrict__ perm) {
    __shared__ int hist[BSZ];
    __shared__ int lofs[BSZ];
    __shared__ int dh[64];
    __shared__ int dbase_s[64];
    int bin = blockIdx.x, t = threadIdx.x;
    // local exclusive prefix of btot over 196 bins (inclusive scan, then shift)
    int pv = (t < NB) ? btot[t] : 0;
    lofs[t] = pv;
    __syncthreads();
    for (int off = 1; off < BSZ; off <<= 1) {
        int u = (t >= off) ? lofs[t - off] : 0;
        __syncthreads();
        lofs[t] += u;
        __syncthreads();
    }
    int base = (bin > 0) ? lofs[bin - 1] : 0;   // broadcast LDS read
    int cnt = btot[bin];
    __syncthreads();
    hist[t] = 0;
    __syncthreads();
    for (int i = t; i < cnt; i += BSZ)
        atomicAdd(&hist[pairs[base + i] & (BSZ - 1)], 1);
    __syncthreads();
    int v = hist[t];
    lofs[t] = v;
    __syncthreads();
    for (int off = 1; off < BSZ; off <<= 1) {
        int u = (t >= off) ? lofs[t - off] : 0;
        __syncthreads();
        lofs[t] += u;
        __syncthreads();
    }
    int excl = lofs[t] - v;
    int d_global = (bin << BSHIFT) + t;
    if (d_global < N_NODES) rowptr[d_global] = base + excl;
    if (bin == NB - 1 && t == 0) rowptr[N_NODES] = base + cnt;
    __syncthreads();
    lofs[t] = excl;
    hist[t] = 0;
    __syncthreads();
    for (int i = t; i < cnt; i += BSZ) {
        uint_t p = pairs[base + i];
        int lb = p & (BSZ - 1);
        int r = atomicAdd(&hist[lb], 1);
        csr[base + lofs[lb] + r] = (int)(p >> BSHIFT);
    }
    // ---- degree-balanced permutation (counting sort by degree, 64 bins) ----
    int dcl = (v > 63) ? 63 : v;
    if (t < 64) dh[t] = 0;
    __syncthreads();
    if (d_global < N_NODES) atomicAdd(&dh[dcl], 1);
    __syncthreads();
    if (t == 0) {
        int s = 0;
        for (int i = 0; i < 64; ++i) { dbase_s[i] = s; s += dh[i]; }
    }
    __syncthreads();
    if (t < 64) dh[t] = 0;    // reuse as per-class cursor
    __syncthreads();
    if (d_global < N_NODES) {
        int rk = atomicAdd(&dh[dcl], 1);
        perm[(bin << BSHIFT) + dbase_s[dcl] + rk] = d_global;
    }
}

// ---------------------------------------------------------------------------
// agg1: h = relu(mean y1[src] + b1 + z1). Nodes processed in degree-sorted
// perm order (waves see ~uniform degree). Writes h as bf16 (hb) AND fp8
// 64-B rows (hf8). 4-lane group = one node (16 nodes/wave).
// ---------------------------------------------------------------------------
__device__ __forceinline__ void acc16(float* acc, uint4 v) {
    f2v_t p;
    p = fp8x2_dec_lo(v.x); acc[0]  += p[0]; acc[1]  += p[1];
    p = fp8x2_dec_hi(v.x); acc[2]  += p[0]; acc[3]  += p[1];
    p = fp8x2_dec_lo(v.y); acc[4]  += p[0]; acc[5]  += p[1];
    p = fp8x2_dec_hi(v.y); acc[6]  += p[0]; acc[7]  += p[1];
    p = fp8x2_dec_lo(v.z); acc[8]  += p[0]; acc[9]  += p[1];
    p = fp8x2_dec_hi(v.z); acc[10] += p[0]; acc[11] += p[1];
    p = fp8x2_dec_lo(v.w); acc[12] += p[0]; acc[13] += p[1];
    p = fp8x2_dec_hi(v.w); acc[14] += p[0]; acc[15] += p[1];
}

__global__ void agg1_kernel(const int* __restrict__ rowptr,
                            const int* __restrict__ csr,
                            const int* __restrict__ perm,
                            const uchar_t* __restrict__ y1f8,
                            const ushort_t* __restrict__ z1b,
                            const float* __restrict__ b1,
                            ushort_t* __restrict__ hb,
                            uchar_t* __restrict__ hf8) {
    int gid = blockIdx.x * blockDim.x + threadIdx.x;
    int wave = gid >> 6, lane = gid & 63;
    int g = lane >> 2, l = lane & 3;
    int idx = wave * 16 + g;
    if (idx >= N_NODES) return;
    int n = perm[idx];
    int beg = rowptr[n], end = rowptr[n + 1];
    float acc[16];
#pragma unroll
    for (int j = 0; j < 16; ++j) acc[j] = 0.f;
    const uchar_t* yb = y1f8 + l * 16;
    int i = beg;
    for (; i + 3 < end; i += 4) {
        int s0 = csr[i], s1 = csr[i + 1], s2 = csr[i + 2], s3 = csr[i + 3];
        uint4 w0 = *(const uint4*)(yb + (size_t)s0 * 64);
        uint4 w1 = *(const uint4*)(yb + (size_t)s1 * 64);
        uint4 w2 = *(const uint4*)(yb + (size_t)s2 * 64);
        uint4 w3 = *(const uint4*)(yb + (size_t)s3 * 64);
        acc16(acc, w0); acc16(acc, w1); acc16(acc, w2); acc16(acc, w3);
    }
    for (; i < end; ++i) {
        uint4 w = *(const uint4*)(yb + (size_t)csr[i] * 64);
        acc16(acc, w);
    }
    float inv = 1.0f / fmaxf((float)(end - beg), 1.0f);
    int c = l * 16;
    ushort_t zz[16];
    *(uint4*)&zz[0] = *(const uint4*)(z1b + (size_t)n * HID + c);
    *(uint4*)&zz[8] = *(const uint4*)(z1b + (size_t)n * HID + c + 8);
    float bv[16];
    *(float4*)&bv[0]  = *(const float4*)(b1 + c);
    *(float4*)&bv[4]  = *(const float4*)(b1 + c + 4);
    *(float4*)&bv[8]  = *(const float4*)(b1 + c + 8);
    *(float4*)&bv[12] = *(const float4*)(b1 + c + 12);
    ushort_t o[16];
    uchar_t of[16];
#pragma unroll
    for (int j = 0; j < 16; ++j) {
        float r = fmaxf(fmaf(acc[j], inv, bv[j] + b2f(zz[j])), 0.f);
        o[j] = f2b(r);
        of[j] = fp8_enc(r);
    }
    *(uint4*)(hb + (size_t)n * HID + c)     = *(const uint4*)&o[0];
    *(uint4*)(hb + (size_t)n * HID + c + 8) = *(const uint4*)&o[8];
    *(uint4*)(hf8 + (size_t)n * 64 + c)     = *(const uint4*)&of[0];
}

// ---------------------------------------------------------------------------
// layer2_fused: per wave, (a) mean-aggregate hf8 for its 16 nodes, stage
// mean_h in LDS; (b) dual-MFMA logits = mean_h @ W2l + h @ W2r + b2 with
// in-register log_softmax; (c) contiguous f32 stores.
// ---------------------------------------------------------------------------
__global__ void layer2_fused_kernel(const int* __restrict__ rowptr,
                                    const int* __restrict__ csr,
                                    const uchar_t* __restrict__ hf8,
                                    const ushort_t* __restrict__ hb,
                                    const ushort_t* __restrict__ W2t,
                                    const float* __restrict__ b2,
                                    float* __restrict__ out) {
    __shared__ ushort_t sA[64][72];    // mean_h bf16, rows padded 64->72
    __shared__ float sO[64][44];       // f32 out tile, rows padded 40->44
    int tid = threadIdx.x;
    int wave = tid >> 6, lane = tid & 63;
    int m0b = blockIdx.x * 64;
    int tileN = m0b + wave * 16;
    bool valid = (tileN < N_NODES);    // N % 16 == 0: tile fully valid or not

    if (valid) {
        int g = lane >> 2, l = lane & 3;
        int n = tileN + g;
        int beg = rowptr[n], end = rowptr[n + 1];
        float acc[16];
#pragma unroll
        for (int j = 0; j < 16; ++j) acc[j] = 0.f;
        const uchar_t* yb = hf8 + l * 16;
        int i = beg;
        for (; i + 3 < end; i += 4) {
            int s0 = csr[i], s1 = csr[i + 1], s2 = csr[i + 2], s3 = csr[i + 3];
            uint4 w0 = *(const uint4*)(yb + (size_t)s0 * 64);
            uint4 w1 = *(const uint4*)(yb + (size_t)s1 * 64);
            uint4 w2 = *(const uint4*)(yb + (size_t)s2 * 64);
            uint4 w3 = *(const uint4*)(yb + (size_t)s3 * 64);
            acc16(acc, w0); acc16(acc, w1); acc16(acc, w2); acc16(acc, w3);
        }
        for (; i < end; ++i) {
            uint4 w = *(const uint4*)(yb + (size_t)csr[i] * 64);
            acc16(acc, w);
        }
        float inv = 1.0f / fmaxf((float)(end - beg), 1.0f);
        ushort_t o[16];
#pragma unroll
        for (int j = 0; j < 16; ++j)
            o[j] = f2b(acc[j] * inv);
        int lrow = wave * 16 + g;
        *(uint4*)&sA[lrow][l * 16]     = *(const uint4*)&o[0];
        *(uint4*)&sA[lrow][l * 16 + 8] = *(const uint4*)&o[8];
    }
    __syncthreads();
    if (valid) {
        int r = lane & 15, q = lane >> 4;
        const ushort_t* ar = &sA[wave * 16 + r][q * 8];
        const ushort_t* hr = hb + (size_t)(tileN + r) * HID + q * 8;
        bf8_t a0[2], a1[2];
#pragma unroll
        for (int kt = 0; kt < 2; ++kt) {
            a0[kt] = *(const bf8_t*)(ar + kt * 32);
            a1[kt] = *(const bf8_t*)(hr + kt * 32);
        }
        float v[3][4];
#pragma unroll
        for (int tn = 0; tn < 3; ++tn) {
            int col = tn * 16 + r;
            int cl = (col < N_CLS) ? col : 0;      // clamp; masked below
            const ushort_t* wl  = W2t + (size_t)cl * HID + q * 8;
            const ushort_t* wr2 = W2t + (size_t)(N_CLS + cl) * HID + q * 8;
            f4_t acc4 = {0.f, 0.f, 0.f, 0.f};
#pragma unroll
            for (int kt = 0; kt < 2; ++kt) {
                bf8_t bl = *(const bf8_t*)(wl + kt * 32);
                acc4 = __builtin_amdgcn_mfma_f32_16x16x32_bf16(a0[kt], bl, acc4, 0, 0, 0);
            }
#pragma unroll
            for (int kt = 0; kt < 2; ++kt) {
                bf8_t br = *(const bf8_t*)(wr2 + kt * 32);
                acc4 = __builtin_amdgcn_mfma_f32_16x16x32_bf16(a1[kt], br, acc4, 0, 0, 0);
            }
            float bias = (col < N_CLS) ? b2[cl] : 0.f;
#pragma unroll
            for (int rr = 0; rr < 4; ++rr)
                v[tn][rr] = (col < N_CLS) ? (acc4[rr] + bias) : -INFINITY;
        }
        // log_softmax per row (row = q*4+rr): reduce over tn (local) and the
        // 16 r-lanes (xor offsets 1..8 stay within the same q group).
        int lrow = wave * 16 + q * 4;
#pragma unroll
        for (int rr = 0; rr < 4; ++rr) {
            float m = fmaxf(fmaxf(v[0][rr], v[1][rr]), v[2][rr]);
#pragma unroll
            for (int off = 1; off < 16; off <<= 1)
                m = fmaxf(m, __shfl_xor(m, off, 64));
            float s = 0.f;
#pragma unroll
            for (int tn = 0; tn < 3; ++tn)
                if (v[tn][rr] > -INFINITY) s += expf(v[tn][rr] - m);
#pragma unroll
            for (int off = 1; off < 16; off <<= 1)
                s += __shfl_xor(s, off, 64);
            float ls = m + logf(s);
#pragma unroll
            for (int tn = 0; tn < 3; ++tn) {
                int col = tn * 16 + r;
                if (col < N_CLS)
                    sO[lrow + rr][col] = v[tn][rr] - ls;
            }
        }
    }
    __syncthreads();
    int vrows = N_NODES - m0b; if (vrows > 64) vrows = 64;
    for (int idx = tid; idx < vrows * 10; idx += 256) {
        int row = idx / 10, c = (idx - row * 10) * 4;   // floats; 4 = 16 B
        *(float4*)(out + (size_t)(m0b + row) * N_CLS + c) = *(const float4*)&sO[row][c];
    }
}

extern "C" void kernel_launch(void* const* d_in, const int* in_sizes, int n_in,
                              void* d_out, int out_size, void* d_ws, size_t ws_size,
                              hipStream_t stream) {
    const float* x   = (const float*)d_in[0];
    const int*   ei  = (const int*)d_in[1];
    const float* W1l = (const float*)d_in[2];
    const float* b1  = (const float*)d_in[3];
    const float* W1r = (const float*)d_in[4];
    const float* W2l = (const float*)d_in[5];
    const float* b2  = (const float*)d_in[6];
    const float* W2r = (const float*)d_in[7];
    float* out = (float*)d_out;
    const int E = in_sizes[1] / 2;
    const int nblk = (E + EPB - 1) / EPB;

    char* p = (char*)d_ws;
    auto take = [&](size_t bytes) {
        char* q = p;
        p += (bytes + 15) & ~(size_t)15;
        return (void*)q;
    };
    int* rowptr     = (int*)take(sizeof(int) * (N_NODES + 4));
    int* blockHist  = (int*)take(sizeof(int) * (size_t)nblk * NB);
    int* blockBase  = (int*)take(sizeof(int) * (size_t)nblk * NB);
    int* btot       = (int*)take(sizeof(int) * NB);
    uint_t* pairs   = (uint_t*)take(sizeof(uint_t) * (size_t)E);
    int* csr        = (int*)take(sizeof(int) * (size_t)E);
    int* perm       = (int*)take(sizeof(int) * N_NODES);
    ushort_t* W1t   = (ushort_t*)take(sizeof(ushort_t) * 128 * F_IN);
    ushort_t* W2t   = (ushort_t*)take(sizeof(ushort_t) * 80 * HID);
    uchar_t* y1f8   = (uchar_t*)take(sizeof(uchar_t) * (size_t)N_NODES * 64);
    ushort_t* z1b   = (ushort_t*)take(sizeof(ushort_t) * (size_t)N_NODES * HID);
    ushort_t* hb    = (ushort_t*)take(sizeof(ushort_t) * (size_t)N_NODES * HID);
    uchar_t* hf8    = (uchar_t*)take(sizeof(uchar_t) * (size_t)N_NODES * 64);

    const int B = 256;

    int cvt_blocks = (128 * F_IN + 80 * HID + B - 1) / B;
    int gemm1_blocks = (MT + 7) / 8;    // 8 tiles (128 rows) per block
    int l2_blocks = (N_NODES + 63) / 64;
    int t_agg = (N_NODES / 16) * 64;    // 16 nodes per wave (4-lane groups)

    hist_cvt_kernel<<<nblk + cvt_blocks, B, 0, stream>>>(
        ei, E, nblk, blockHist, W1l, W1r, W2l, W2r, W1t, W2t);
    scan_gemm1_kernel<<<NB + gemm1_blocks, B, 0, stream>>>(
        blockHist, nblk, blockBase, btot, x, W1t, y1f8, z1b);
    scatter_pairs_kernel<<<nblk, 256, 0, stream>>>(ei, E, blockBase, btot, pairs);
    bucket_sort_kernel<<<NB, BSZ, 0, stream>>>(pairs, btot, rowptr, csr, perm);
    agg1_kernel<<<(t_agg + B - 1) / B, B, 0, stream>>>(rowptr, csr, perm, y1f8, z1b, b1, hb, hf8);
    layer2_fused_kernel<<<l2_blocks, B, 0, stream>>>(rowptr, csr, hf8, hb, W2t, b2, out);
}

// Round 14
// 226.828 us; speedup vs baseline: 1.0545x; 1.0545x over previous
//
#include <hip/hip_runtime.h>
#include <math.h>

#define N_NODES 100000
#define F_IN    128
#define HID     64
#define N_CLS   40
#define MT      (N_NODES / 16)                  // 6250 M-tiles of 16 nodes

#define BSHIFT  9
#define BSZ     512                              // dsts per coarse bucket
#define NB      ((N_NODES + BSZ - 1) / BSZ)      // 196 buckets
#define EPB     4096                             // edges per block in sort passes

typedef __attribute__((ext_vector_type(8))) short bf8_t;   // 8 bf16 (4 VGPR)
typedef __attribute__((ext_vector_type(4))) float f4_t;    // MFMA C/D frag
typedef __attribute__((ext_vector_type(2))) float f2v_t;

typedef unsigned short ushort_t;
typedef unsigned int uint_t;
typedef unsigned char uchar_t;

__device__ __forceinline__ ushort_t f2b(float f) {   // f32 -> bf16 RNE
    union { float f; uint_t u; } c; c.f = f;
    uint_t u = c.u + 0x7FFFu + ((c.u >> 16) & 1u);
    return (ushort_t)(u >> 16);
}
__device__ __forceinline__ float b2f(ushort_t h) {
    union { uint_t u; float f; } c; c.u = ((uint_t)h) << 16;
    return c.f;
}

// ---- fp8 e4m3 (OCP) helpers: HW cvt if available, manual fallback ---------
#if defined(__has_builtin)
#if __has_builtin(__builtin_amdgcn_cvt_pk_f32_fp8) && __has_builtin(__builtin_amdgcn_cvt_pk_fp8_f32)
#define HAVE_FP8_HW 1
#endif
#endif

__device__ __forceinline__ uchar_t fp8_enc(float v) {
#ifdef HAVE_FP8_HW
    return (uchar_t)(__builtin_amdgcn_cvt_pk_fp8_f32(v, v, 0, false) & 0xff);
#else
    union { float f; uint_t u; } c; c.f = v;
    uint_t s = c.u >> 31;
    float av = fabsf(v);
    if (av > 448.f) av = 448.f;
    int e;
    float m = frexpf(av, &e);          // av = m * 2^e, m in [0.5,1)
    int ee = e + 6;                    // biased for e4m3 (bias 7, m in [1,2))
    uchar_t r;
    if (av == 0.f) r = 0;
    else if (ee <= 0) {                // denormal
        int q = (int)(av * 512.f + 0.5f);   // units of 2^-9
        if (q > 7) q = 7;
        r = (uchar_t)q;
    } else {
        int q = (int)(m * 16.f + 0.5f);     // m*16 in [8,16]
        if (q == 16) { q = 8; ee += 1; }
        if (ee > 15) { ee = 15; q = 15; }   // clamp toward max finite
        r = (uchar_t)((ee << 3) | (q & 7));
    }
    return r | (uchar_t)(s << 7);
#endif
}

__device__ __forceinline__ f2v_t fp8x2_dec_lo(uint_t w) {
#ifdef HAVE_FP8_HW
    return __builtin_amdgcn_cvt_pk_f32_fp8(w, false);
#else
    f2v_t r;
    for (int k = 0; k < 2; ++k) {
        uchar_t b = (w >> (8 * k)) & 0xff;
        uint_t s = (b >> 7) & 1, e = (b >> 3) & 15, m = b & 7;
        float f;
        if (e) { union { uint_t u; float ff; } c;
                 c.u = (s << 31) | ((e + 120) << 23) | (m << 20); f = c.ff; }
        else   { f = (float)m * 0.001953125f; if (s) f = -f; }
        r[k] = f;
    }
    return r;
#endif
}
__device__ __forceinline__ f2v_t fp8x2_dec_hi(uint_t w) {
#ifdef HAVE_FP8_HW
    return __builtin_amdgcn_cvt_pk_f32_fp8(w, true);
#else
    return fp8x2_dec_lo(w >> 16);
#endif
}

// ---------------------------------------------------------------------------
// hist_cvt: grid-partitioned fusion. Blocks [0,nblk): per-block LDS histogram
// over 196 coarse buckets. Blocks [nblk, ...): weight conversion to bf16.
// ---------------------------------------------------------------------------
__global__ void hist_cvt_kernel(const int* __restrict__ ei, int E, int nblk,
                                int* __restrict__ blockHist,
                                const float* __restrict__ W1l,
                                const float* __restrict__ W1r,
                                const float* __restrict__ W2l,
                                const float* __restrict__ W2r,
                                ushort_t* __restrict__ W1t,
                                ushort_t* __restrict__ W2t) {
    __shared__ int cnt[NB];
    int t = threadIdx.x;
    if ((int)blockIdx.x < nblk) {
        int blk = blockIdx.x;
        for (int i = t; i < NB; i += 256) cnt[i] = 0;
        __syncthreads();
        int e0 = blk * EPB;
#pragma unroll
        for (int i = 0; i < EPB / 256; ++i) {
            int e = e0 + i * 256 + t;
            if (e < E) atomicAdd(&cnt[ei[E + e] >> BSHIFT], 1);
        }
        __syncthreads();
        for (int i = t; i < NB; i += 256) blockHist[blk * NB + i] = cnt[i];
    } else {
        int u = (blockIdx.x - nblk) * 256 + t;
        if (u < 128 * F_IN) {
            int n = u / F_IN, k = u - n * F_IN;
            float v = (n < HID) ? W1l[k * HID + n] : W1r[k * HID + (n - HID)];
            W1t[u] = f2b(v);
        } else if (u < 128 * F_IN + 80 * HID) {
            int w = u - 128 * F_IN;
            int n = w / HID, k = w - n * HID;
            float v = (n < N_CLS) ? W2l[k * N_CLS + n] : W2r[k * N_CLS + (n - N_CLS)];
            W2t[w] = f2b(v);
        }
    }
}

// ---------------------------------------------------------------------------
// scan_gemm1: grid-partitioned fusion. Blocks [0,NB): per-bin exclusive scan
// down the sort blocks (col_scan). Blocks [NB, ...): gemm1 (independent of
// the sort chain) — runs concurrently inside one dispatch, hiding the scan.
// ---------------------------------------------------------------------------
__global__ void scan_gemm1_kernel(const int* __restrict__ blockHist, int nblk,
                                  int* __restrict__ blockBase,
                                  int* __restrict__ btot,
                                  const float* __restrict__ x,
                                  const ushort_t* __restrict__ W1t,
                                  uchar_t* __restrict__ y1f8,
                                  ushort_t* __restrict__ z1b) {
    __shared__ int ss[256];
    __shared__ int carry;
    __shared__ uchar_t sy[128][80];    // 10240 B, rows padded 64->80
    __shared__ ushort_t sz[128][72];   // 18432 B, rows padded 64->72
    int t = threadIdx.x;
    if (blockIdx.x < NB) {
        int bin = blockIdx.x;
        if (t == 0) carry = 0;
        __syncthreads();
        for (int c0 = 0; c0 < nblk; c0 += 256) {
            int b = c0 + t;
            int v = (b < nblk) ? blockHist[b * NB + bin] : 0;
            ss[t] = v;
            __syncthreads();
            for (int off = 1; off < 256; off <<= 1) {
                int u = (t >= off) ? ss[t - off] : 0;
                __syncthreads();
                ss[t] += u;
                __syncthreads();
            }
            if (b < nblk) blockBase[b * NB + bin] = carry + ss[t] - v;
            __syncthreads();
            if (t == 255) carry += ss[255];
            __syncthreads();
        }
        if (t == 0) btot[bin] = carry;
        return;
    }
    // ---- gemm1 body (block id rebased) ----
    int gblk = blockIdx.x - NB;
    int tid = t;
    int wave = tid >> 6, lane = tid & 63;
    int tile0 = gblk * 8 + wave * 2;           // 2 consecutive tiles per wave
    int m0b = gblk * 128;
    int r = lane & 15, q = lane >> 4;
    bool v0 = (tile0 < MT), v1 = (tile0 + 1 < MT);

    bf8_t a0[4], a1[4];
#pragma unroll
    for (int kt = 0; kt < 4; ++kt) { a0[kt] = (bf8_t)(short)0; a1[kt] = (bf8_t)(short)0; }
    if (v0) {
        const float* xr = x + (size_t)(tile0 * 16 + r) * F_IN + q * 8;
#pragma unroll
        for (int kt = 0; kt < 4; ++kt) {
            float4 u = *(const float4*)(xr + kt * 32);
            float4 v = *(const float4*)(xr + kt * 32 + 4);
            bf8_t tt;
            tt[0] = (short)f2b(u.x); tt[1] = (short)f2b(u.y);
            tt[2] = (short)f2b(u.z); tt[3] = (short)f2b(u.w);
            tt[4] = (short)f2b(v.x); tt[5] = (short)f2b(v.y);
            tt[6] = (short)f2b(v.z); tt[7] = (short)f2b(v.w);
            a0[kt] = tt;
        }
    }
    if (v1) {
        const float* xr = x + (size_t)((tile0 + 1) * 16 + r) * F_IN + q * 8;
#pragma unroll
        for (int kt = 0; kt < 4; ++kt) {
            float4 u = *(const float4*)(xr + kt * 32);
            float4 v = *(const float4*)(xr + kt * 32 + 4);
            bf8_t tt;
            tt[0] = (short)f2b(u.x); tt[1] = (short)f2b(u.y);
            tt[2] = (short)f2b(u.z); tt[3] = (short)f2b(u.w);
            tt[4] = (short)f2b(v.x); tt[5] = (short)f2b(v.y);
            tt[6] = (short)f2b(v.z); tt[7] = (short)f2b(v.w);
            a1[kt] = tt;
        }
    }
    int lr0 = wave * 32 + q * 4;       // row base within block for tile 0
#pragma unroll
    for (int tn = 0; tn < 8; ++tn) {
        const ushort_t* wr = W1t + (size_t)(tn * 16 + r) * F_IN + q * 8;
        bf8_t b[4];
#pragma unroll
        for (int kt = 0; kt < 4; ++kt)
            b[kt] = *(const bf8_t*)(wr + kt * 32);
        f4_t acc0 = {0.f, 0.f, 0.f, 0.f};
        f4_t acc1 = {0.f, 0.f, 0.f, 0.f};
#pragma unroll
        for (int kt = 0; kt < 4; ++kt) {
            acc0 = __builtin_amdgcn_mfma_f32_16x16x32_bf16(a0[kt], b[kt], acc0, 0, 0, 0);
            acc1 = __builtin_amdgcn_mfma_f32_16x16x32_bf16(a1[kt], b[kt], acc1, 0, 0, 0);
        }
        int col = tn * 16 + r;
        if (col < 64) {
            if (v0) {
#pragma unroll
                for (int rr = 0; rr < 4; ++rr) sy[lr0 + rr][col] = fp8_enc(acc0[rr]);
            }
            if (v1) {
#pragma unroll
                for (int rr = 0; rr < 4; ++rr) sy[lr0 + 16 + rr][col] = fp8_enc(acc1[rr]);
            }
        } else {
            if (v0) {
#pragma unroll
                for (int rr = 0; rr < 4; ++rr) sz[lr0 + rr][col - 64] = f2b(acc0[rr]);
            }
            if (v1) {
#pragma unroll
                for (int rr = 0; rr < 4; ++rr) sz[lr0 + 16 + rr][col - 64] = f2b(acc1[rr]);
            }
        }
    }
    __syncthreads();
    int vrows = N_NODES - m0b; if (vrows > 128) vrows = 128;
    for (int idx = tid; idx < vrows * 4; idx += 256) {
        int row = idx >> 2, c = (idx & 3) << 4;
        *(uint4*)(y1f8 + (size_t)(m0b + row) * 64 + c) = *(const uint4*)&sy[row][c];
    }
    for (int idx = tid; idx < vrows * 8; idx += 256) {
        int row = idx >> 3, c = (idx & 7) << 3;      // ushort offset, 8 = 16 B
        *(uint4*)(z1b + (size_t)(m0b + row) * HID + c) = *(const uint4*)&sz[row][c];
    }
}

// ---------------------------------------------------------------------------
// Sort pass 3: scatter packed (src<<9 | dst&511) into coarse-bucket order.
// Bucket base offsets computed locally from btot (196-elem LDS scan).
// ---------------------------------------------------------------------------
__global__ void scatter_pairs_kernel(const int* __restrict__ ei, int E,
                                     const int* __restrict__ blockBase,
                                     const int* __restrict__ btot,
                                     uint_t* __restrict__ pairs) {
    __shared__ int cur[NB];
    __shared__ int base[NB];
    __shared__ int ss[256];
    int t = threadIdx.x, blk = blockIdx.x;
    int v = (t < NB) ? btot[t] : 0;
    ss[t] = v;
    __syncthreads();
    for (int off = 1; off < 256; off <<= 1) {
        int u = (t >= off) ? ss[t - off] : 0;
        __syncthreads();
        ss[t] += u;
        __syncthreads();
    }
    if (t < NB) {
        cur[t] = 0;
        base[t] = (ss[t] - v) + blockBase[blk * NB + t];
    }
    __syncthreads();
    int e0 = blk * EPB;
#pragma unroll
    for (int i = 0; i < EPB / 256; ++i) {
        int e = e0 + i * 256 + t;
        if (e < E) {
            int src = ei[e];
            int dst = ei[E + e];
            int bin = dst >> BSHIFT;
            int r = atomicAdd(&cur[bin], 1);   // LDS atomic
            pairs[base[bin] + r] = ((uint_t)src << BSHIFT) | (uint_t)(dst & (BSZ - 1));
        }
    }
}

// ---------------------------------------------------------------------------
// Sort pass 4: per-bucket fine sort. Bucket base computed locally
// from btot; rowptr + contiguous csr region; rowptr[N] written by last bin.
// ---------------------------------------------------------------------------
__global__ void bucket_sort_kernel(const uint_t* __restrict__ pairs,
                                   const int* __restrict__ btot,
                                   int* __restrict__ rowptr,
                                   int* __restrict__ csr) {
    __shared__ int hist[BSZ];
    __shared__ int lofs[BSZ];
    int bin = blockIdx.x, t = threadIdx.x;
    // local exclusive prefix of btot over 196 bins (inclusive scan, then shift)
    int pv = (t < NB) ? btot[t] : 0;
    lofs[t] = pv;
    __syncthreads();
    for (int off = 1; off < BSZ; off <<= 1) {
        int u = (t >= off) ? lofs[t - off] : 0;
        __syncthreads();
        lofs[t] += u;
        __syncthreads();
    }
    int base = (bin > 0) ? lofs[bin - 1] : 0;   // broadcast LDS read
    int cnt = btot[bin];
    __syncthreads();
    hist[t] = 0;
    __syncthreads();
    for (int i = t; i < cnt; i += BSZ)
        atomicAdd(&hist[pairs[base + i] & (BSZ - 1)], 1);
    __syncthreads();
    int v = hist[t];
    lofs[t] = v;
    __syncthreads();
    for (int off = 1; off < BSZ; off <<= 1) {
        int u = (t >= off) ? lofs[t - off] : 0;
        __syncthreads();
        lofs[t] += u;
        __syncthreads();
    }
    int excl = lofs[t] - v;
    int d_global = (bin << BSHIFT) + t;
    if (d_global < N_NODES) rowptr[d_global] = base + excl;
    if (bin == NB - 1 && t == 0) rowptr[N_NODES] = base + cnt;
    __syncthreads();
    lofs[t] = excl;
    hist[t] = 0;
    __syncthreads();
    for (int i = t; i < cnt; i += BSZ) {
        uint_t p = pairs[base + i];
        int lb = p & (BSZ - 1);
        int r = atomicAdd(&hist[lb], 1);
        csr[base + lofs[lb] + r] = (int)(p >> BSHIFT);
    }
}

// ---------------------------------------------------------------------------
// agg1: h = relu(mean y1[src] + b1 + z1). Natural node order (coalesced
// epilogue IO — r13's perm reorder lost more in scattered z1b/hb/hf8 traffic
// than it gained in degree balance). Writes h as bf16 (hb) AND fp8 (hf8).
// 4-lane group = one node (16 nodes/wave).
// ---------------------------------------------------------------------------
__device__ __forceinline__ void acc16(float* acc, uint4 v) {
    f2v_t p;
    p = fp8x2_dec_lo(v.x); acc[0]  += p[0]; acc[1]  += p[1];
    p = fp8x2_dec_hi(v.x); acc[2]  += p[0]; acc[3]  += p[1];
    p = fp8x2_dec_lo(v.y); acc[4]  += p[0]; acc[5]  += p[1];
    p = fp8x2_dec_hi(v.y); acc[6]  += p[0]; acc[7]  += p[1];
    p = fp8x2_dec_lo(v.z); acc[8]  += p[0]; acc[9]  += p[1];
    p = fp8x2_dec_hi(v.z); acc[10] += p[0]; acc[11] += p[1];
    p = fp8x2_dec_lo(v.w); acc[12] += p[0]; acc[13] += p[1];
    p = fp8x2_dec_hi(v.w); acc[14] += p[0]; acc[15] += p[1];
}

__global__ void agg1_kernel(const int* __restrict__ rowptr,
                            const int* __restrict__ csr,
                            const uchar_t* __restrict__ y1f8,
                            const ushort_t* __restrict__ z1b,
                            const float* __restrict__ b1,
                            ushort_t* __restrict__ hb,
                            uchar_t* __restrict__ hf8) {
    int gid = blockIdx.x * blockDim.x + threadIdx.x;
    int wave = gid >> 6, lane = gid & 63;
    int g = lane >> 2, l = lane & 3;
    int n = wave * 16 + g;                // N_NODES % 16 == 0
    if (n >= N_NODES) return;
    int beg = rowptr[n], end = rowptr[n + 1];
    float acc[16];
#pragma unroll
    for (int j = 0; j < 16; ++j) acc[j] = 0.f;
    const uchar_t* yb = y1f8 + l * 16;
    int i = beg;
    for (; i + 3 < end; i += 4) {
        int s0 = csr[i], s1 = csr[i + 1], s2 = csr[i + 2], s3 = csr[i + 3];
        uint4 w0 = *(const uint4*)(yb + (size_t)s0 * 64);
        uint4 w1 = *(const uint4*)(yb + (size_t)s1 * 64);
        uint4 w2 = *(const uint4*)(yb + (size_t)s2 * 64);
        uint4 w3 = *(const uint4*)(yb + (size_t)s3 * 64);
        acc16(acc, w0); acc16(acc, w1); acc16(acc, w2); acc16(acc, w3);
    }
    for (; i < end; ++i) {
        uint4 w = *(const uint4*)(yb + (size_t)csr[i] * 64);
        acc16(acc, w);
    }
    float inv = 1.0f / fmaxf((float)(end - beg), 1.0f);
    int c = l * 16;
    ushort_t zz[16];
    *(uint4*)&zz[0] = *(const uint4*)(z1b + (size_t)n * HID + c);
    *(uint4*)&zz[8] = *(const uint4*)(z1b + (size_t)n * HID + c + 8);
    float bv[16];
    *(float4*)&bv[0]  = *(const float4*)(b1 + c);
    *(float4*)&bv[4]  = *(const float4*)(b1 + c + 4);
    *(float4*)&bv[8]  = *(const float4*)(b1 + c + 8);
    *(float4*)&bv[12] = *(const float4*)(b1 + c + 12);
    ushort_t o[16];
    uchar_t of[16];
#pragma unroll
    for (int j = 0; j < 16; ++j) {
        float r = fmaxf(fmaf(acc[j], inv, bv[j] + b2f(zz[j])), 0.f);
        o[j] = f2b(r);
        of[j] = fp8_enc(r);
    }
    *(uint4*)(hb + (size_t)n * HID + c)     = *(const uint4*)&o[0];
    *(uint4*)(hb + (size_t)n * HID + c + 8) = *(const uint4*)&o[8];
    *(uint4*)(hf8 + (size_t)n * 64 + c)     = *(const uint4*)&of[0];
}

// ---------------------------------------------------------------------------
// layer2_fused: per wave, (a) mean-aggregate hf8 for its 16 nodes, stage
// mean_h in LDS; (b) dual-MFMA logits = mean_h @ W2l + h @ W2r + b2 with
// in-register log_softmax; (c) contiguous f32 stores.
// ---------------------------------------------------------------------------
__global__ void layer2_fused_kernel(const int* __restrict__ rowptr,
                                    const int* __restrict__ csr,
                                    const uchar_t* __restrict__ hf8,
                                    const ushort_t* __restrict__ hb,
                                    const ushort_t* __restrict__ W2t,
                                    const float* __restrict__ b2,
                                    float* __restrict__ out) {
    __shared__ ushort_t sA[64][72];    // mean_h bf16, rows padded 64->72
    __shared__ float sO[64][44];       // f32 out tile, rows padded 40->44
    int tid = threadIdx.x;
    int wave = tid >> 6, lane = tid & 63;
    int m0b = blockIdx.x * 64;
    int tileN = m0b + wave * 16;
    bool valid = (tileN < N_NODES);    // N % 16 == 0: tile fully valid or not

    if (valid) {
        int g = lane >> 2, l = lane & 3;
        int n = tileN + g;
        int beg = rowptr[n], end = rowptr[n + 1];
        float acc[16];
#pragma unroll
        for (int j = 0; j < 16; ++j) acc[j] = 0.f;
        const uchar_t* yb = hf8 + l * 16;
        int i = beg;
        for (; i + 3 < end; i += 4) {
            int s0 = csr[i], s1 = csr[i + 1], s2 = csr[i + 2], s3 = csr[i + 3];
            uint4 w0 = *(const uint4*)(yb + (size_t)s0 * 64);
            uint4 w1 = *(const uint4*)(yb + (size_t)s1 * 64);
            uint4 w2 = *(const uint4*)(yb + (size_t)s2 * 64);
            uint4 w3 = *(const uint4*)(yb + (size_t)s3 * 64);
            acc16(acc, w0); acc16(acc, w1); acc16(acc, w2); acc16(acc, w3);
        }
        for (; i < end; ++i) {
            uint4 w = *(const uint4*)(yb + (size_t)csr[i] * 64);
            acc16(acc, w);
        }
        float inv = 1.0f / fmaxf((float)(end - beg), 1.0f);
        ushort_t o[16];
#pragma unroll
        for (int j = 0; j < 16; ++j)
            o[j] = f2b(acc[j] * inv);
        int lrow = wave * 16 + g;
        *(uint4*)&sA[lrow][l * 16]     = *(const uint4*)&o[0];
        *(uint4*)&sA[lrow][l * 16 + 8] = *(const uint4*)&o[8];
    }
    __syncthreads();
    if (valid) {
        int r = lane & 15, q = lane >> 4;
        const ushort_t* ar = &sA[wave * 16 + r][q * 8];
        const ushort_t* hr = hb + (size_t)(tileN + r) * HID + q * 8;
        bf8_t a0[2], a1[2];
#pragma unroll
        for (int kt = 0; kt < 2; ++kt) {
            a0[kt] = *(const bf8_t*)(ar + kt * 32);
            a1[kt] = *(const bf8_t*)(hr + kt * 32);
        }
        float v[3][4];
#pragma unroll
        for (int tn = 0; tn < 3; ++tn) {
            int col = tn * 16 + r;
            int cl = (col < N_CLS) ? col : 0;      // clamp; masked below
            const ushort_t* wl  = W2t + (size_t)cl * HID + q * 8;
            const ushort_t* wr2 = W2t + (size_t)(N_CLS + cl) * HID + q * 8;
            f4_t acc4 = {0.f, 0.f, 0.f, 0.f};
#pragma unroll
            for (int kt = 0; kt < 2; ++kt) {
                bf8_t bl = *(const bf8_t*)(wl + kt * 32);
                acc4 = __builtin_amdgcn_mfma_f32_16x16x32_bf16(a0[kt], bl, acc4, 0, 0, 0);
            }
#pragma unroll
            for (int kt = 0; kt < 2; ++kt) {
                bf8_t br = *(const bf8_t*)(wr2 + kt * 32);
                acc4 = __builtin_amdgcn_mfma_f32_16x16x32_bf16(a1[kt], br, acc4, 0, 0, 0);
            }
            float bias = (col < N_CLS) ? b2[cl] : 0.f;
#pragma unroll
            for (int rr = 0; rr < 4; ++rr)
                v[tn][rr] = (col < N_CLS) ? (acc4[rr] + bias) : -INFINITY;
        }
        // log_softmax per row (row = q*4+rr): reduce over tn (local) and the
        // 16 r-lanes (xor offsets 1..8 stay within the same q group).
        int lrow = wave * 16 + q * 4;
#pragma unroll
        for (int rr = 0; rr < 4; ++rr) {
            float m = fmaxf(fmaxf(v[0][rr], v[1][rr]), v[2][rr]);
#pragma unroll
            for (int off = 1; off < 16; off <<= 1)
                m = fmaxf(m, __shfl_xor(m, off, 64));
            float s = 0.f;
#pragma unroll
            for (int tn = 0; tn < 3; ++tn)
                if (v[tn][rr] > -INFINITY) s += expf(v[tn][rr] - m);
#pragma unroll
            for (int off = 1; off < 16; off <<= 1)
                s += __shfl_xor(s, off, 64);
            float ls = m + logf(s);
#pragma unroll
            for (int tn = 0; tn < 3; ++tn) {
                int col = tn * 16 + r;
                if (col < N_CLS)
                    sO[lrow + rr][col] = v[tn][rr] - ls;
            }
        }
    }
    __syncthreads();
    int vrows = N_NODES - m0b; if (vrows > 64) vrows = 64;
    for (int idx = tid; idx < vrows * 10; idx += 256) {
        int row = idx / 10, c = (idx - row * 10) * 4;   // floats; 4 = 16 B
        *(float4*)(out + (size_t)(m0b + row) * N_CLS + c) = *(const float4*)&sO[row][c];
    }
}

extern "C" void kernel_launch(void* const* d_in, const int* in_sizes, int n_in,
                              void* d_out, int out_size, void* d_ws, size_t ws_size,
                              hipStream_t stream) {
    const float* x   = (const float*)d_in[0];
    const int*   ei  = (const int*)d_in[1];
    const float* W1l = (const float*)d_in[2];
    const float* b1  = (const float*)d_in[3];
    const float* W1r = (const float*)d_in[4];
    const float* W2l = (const float*)d_in[5];
    const float* b2  = (const float*)d_in[6];
    const float* W2r = (const float*)d_in[7];
    float* out = (float*)d_out;
    const int E = in_sizes[1] / 2;
    const int nblk = (E + EPB - 1) / EPB;

    char* p = (char*)d_ws;
    auto take = [&](size_t bytes) {
        char* q = p;
        p += (bytes + 15) & ~(size_t)15;
        return (void*)q;
    };
    int* rowptr     = (int*)take(sizeof(int) * (N_NODES + 4));
    int* blockHist  = (int*)take(sizeof(int) * (size_t)nblk * NB);
    int* blockBase  = (int*)take(sizeof(int) * (size_t)nblk * NB);
    int* btot       = (int*)take(sizeof(int) * NB);
    uint_t* pairs   = (uint_t*)take(sizeof(uint_t) * (size_t)E);
    int* csr        = (int*)take(sizeof(int) * (size_t)E);
    ushort_t* W1t   = (ushort_t*)take(sizeof(ushort_t) * 128 * F_IN);
    ushort_t* W2t   = (ushort_t*)take(sizeof(ushort_t) * 80 * HID);
    uchar_t* y1f8   = (uchar_t*)take(sizeof(uchar_t) * (size_t)N_NODES * 64);
    ushort_t* z1b   = (ushort_t*)take(sizeof(ushort_t) * (size_t)N_NODES * HID);
    ushort_t* hb    = (ushort_t*)take(sizeof(ushort_t) * (size_t)N_NODES * HID);
    uchar_t* hf8    = (uchar_t*)take(sizeof(uchar_t) * (size_t)N_NODES * 64);

    const int B = 256;

    int cvt_blocks = (128 * F_IN + 80 * HID + B - 1) / B;
    int gemm1_blocks = (MT + 7) / 8;    // 8 tiles (128 rows) per block
    int l2_blocks = (N_NODES + 63) / 64;
    int t_agg = (N_NODES / 16) * 64;    // 16 nodes per wave (4-lane groups)

    hist_cvt_kernel<<<nblk + cvt_blocks, B, 0, stream>>>(
        ei, E, nblk, blockHist, W1l, W1r, W2l, W2r, W1t, W2t);
    scan_gemm1_kernel<<<NB + gemm1_blocks, B, 0, stream>>>(
        blockHist, nblk, blockBase, btot, x, W1t, y1f8, z1b);
    scatter_pairs_kernel<<<nblk, 256, 0, stream>>>(ei, E, blockBase, btot, pairs);
    bucket_sort_kernel<<<NB, BSZ, 0, stream>>>(pairs, btot, rowptr, csr);
    agg1_kernel<<<(t_agg + B - 1) / B, B, 0, stream>>>(rowptr, csr, y1f8, z1b, b1, hb, hf8);
    layer2_fused_kernel<<<l2_blocks, B, 0, stream>>>(rowptr, csr, hf8, hb, W2t, b2, out);
}